// Round 1
// baseline (715.881 us; speedup 1.0000x reference)
//
#include <hip/hip_runtime.h>

#define HH 128
#define WW 256
#define CV_C 32
#define DISP 200

// ---------------------------------------------------------------------------
// Cost volume: cost[d,y,x] = sum_c left[c,y,x] * right[c,y,x+d-200]  (0 if OOB)
// Block: 256 threads (one per x). Grid: (8 d-chunks of 25, H).
// Right row staged in LDS; left row held in 32 VGPRs.
// ---------------------------------------------------------------------------
__global__ __launch_bounds__(256) void cost_volume_kernel(
    const float* __restrict__ left, const float* __restrict__ right,
    float* __restrict__ cost) {
  __shared__ float rsh[CV_C][WW];  // 32 KB
  const int x = threadIdx.x;
  const int y = blockIdx.y;
  const int d0 = blockIdx.x * 25;

  float lreg[CV_C];
#pragma unroll
  for (int c = 0; c < CV_C; ++c) {
    rsh[c][x] = right[(c * HH + y) * WW + x];
    lreg[c] = left[(c * HH + y) * WW + x];
  }
  __syncthreads();

  for (int dd = 0; dd < 25; ++dd) {
    const int d = d0 + dd;
    const int xi = x + d - DISP;
    float acc = 0.f;
    if (xi >= 0) {
#pragma unroll
      for (int c = 0; c < CV_C; ++c) acc += lreg[c] * rsh[c][xi];
    }
    cost[(d * HH + y) * WW + x] = acc;
  }
}

// ---------------------------------------------------------------------------
// Direct 3x3 conv (stride 1, pad 1) + optional BN(eval) + ReLU.
// Block (16,16)=256 threads. Tile: 64 x 16 output pixels, 4 px/thread (in x),
// NCO out-channels/thread (acc[NCO][4] registers).
// Input staged in LDS in chunks of CCH=8 channels with 1-px halo.
// ---------------------------------------------------------------------------
template <int CIN, int NCO, bool BN_RELU>
__global__ __launch_bounds__(256) void conv3x3_kernel(
    const float* __restrict__ in,    // [CIN][H][W]
    const float* __restrict__ wgt,   // [COUT][CIN][3][3]
    const float* __restrict__ bias,  // [COUT]
    const float* __restrict__ gam, const float* __restrict__ bet,
    const float* __restrict__ mean, const float* __restrict__ var,
    float* __restrict__ out) {       // [COUT][H][W]
  constexpr int TW = 64;            // tile width (pixels)
  constexpr int TH = 16;            // tile height
  constexpr int CCH = 8;            // input-channel chunk
  constexpr int HS = TW + 2;        // 66 (halo width)
  constexpr int PS = 68;            // padded LDS row stride (floats)

  __shared__ float ish[CCH][TH + 2][PS];  // 8*18*68*4 = 39168 B
  __shared__ float wsh[CCH][9][NCO];      // <= 2304 B

  const int tx = threadIdx.x;  // 0..15
  const int ty = threadIdx.y;  // 0..15
  const int tid = ty * 16 + tx;
  const int x0 = blockIdx.x * TW;
  const int y0 = blockIdx.y * TH;
  const int co0 = blockIdx.z * NCO;

  float acc[NCO][4];
#pragma unroll
  for (int co = 0; co < NCO; ++co)
#pragma unroll
    for (int p = 0; p < 4; ++p) acc[co][p] = 0.f;

  for (int ci0 = 0; ci0 < CIN; ci0 += CCH) {
    // ---- stage input chunk (with halo, zero-padded at borders) ----
    constexpr int NELEM = CCH * (TH + 2) * HS;
    for (int i = tid; i < NELEM; i += 256) {
      const int ci = i / ((TH + 2) * HS);
      const int rem = i % ((TH + 2) * HS);
      const int yy = rem / HS;
      const int xx = rem % HS;
      const int gy = y0 + yy - 1;
      const int gx = x0 + xx - 1;
      float v = 0.f;
      if (gy >= 0 && gy < HH && gx >= 0 && gx < WW)
        v = in[((ci0 + ci) * HH + gy) * WW + gx];
      ish[ci][yy][xx] = v;
    }
    // ---- stage weight chunk ----
    constexpr int NWEL = CCH * 9 * NCO;
    for (int i = tid; i < NWEL; i += 256) {
      const int ci = i / (9 * NCO);
      const int rem = i % (9 * NCO);
      const int k = rem / NCO;
      const int co = rem % NCO;
      wsh[ci][k][co] = wgt[((co0 + co) * CIN + ci0 + ci) * 9 + k];
    }
    __syncthreads();

    // ---- compute ----
#pragma unroll
    for (int ci = 0; ci < CCH; ++ci) {
#pragma unroll
      for (int ky = 0; ky < 3; ++ky) {
        const float4 v4 =
            *reinterpret_cast<const float4*>(&ish[ci][ty + ky][4 * tx]);
        const float2 v2 =
            *reinterpret_cast<const float2*>(&ish[ci][ty + ky][4 * tx + 4]);
        const float iv[6] = {v4.x, v4.y, v4.z, v4.w, v2.x, v2.y};
#pragma unroll
        for (int kx = 0; kx < 3; ++kx) {
#pragma unroll
          for (int co = 0; co < NCO; ++co) {
            const float wv = wsh[ci][ky * 3 + kx][co];
            acc[co][0] += iv[kx + 0] * wv;
            acc[co][1] += iv[kx + 1] * wv;
            acc[co][2] += iv[kx + 2] * wv;
            acc[co][3] += iv[kx + 3] * wv;
          }
        }
      }
    }
    __syncthreads();
  }

  // ---- epilogue: bias (+ BN + ReLU) ----
  const int oy = y0 + ty;
  const int ox = x0 + 4 * tx;
#pragma unroll
  for (int co = 0; co < NCO; ++co) {
    const int c = co0 + co;
    const float b = bias[c];
    float sc = 1.f, sh = 0.f;
    if (BN_RELU) {
      const float inv = rsqrtf(var[c] + 1e-5f);
      sc = gam[c] * inv;
      sh = bet[c] - mean[c] * sc;
    }
    float4 r;
    float* rp = &r.x;
#pragma unroll
    for (int p = 0; p < 4; ++p) {
      float v = acc[co][p] + b;
      if (BN_RELU) {
        v = v * sc + sh;
        v = fmaxf(v, 0.f);
      }
      rp[p] = v;
    }
    *reinterpret_cast<float4*>(&out[(c * HH + oy) * WW + ox]) = r;
  }
}

// ---------------------------------------------------------------------------
extern "C" void kernel_launch(void* const* d_in, const int* in_sizes, int n_in,
                              void* d_out, int out_size, void* d_ws,
                              size_t ws_size, hipStream_t stream) {
  const float* left = (const float*)d_in[0];
  const float* right = (const float*)d_in[1];
  const float* w1 = (const float*)d_in[2];
  const float* b1 = (const float*)d_in[3];
  const float* g1 = (const float*)d_in[4];
  const float* be1 = (const float*)d_in[5];
  const float* m1 = (const float*)d_in[6];
  const float* v1 = (const float*)d_in[7];
  const float* w2 = (const float*)d_in[8];
  const float* b2 = (const float*)d_in[9];
  const float* g2 = (const float*)d_in[10];
  const float* be2 = (const float*)d_in[11];
  const float* m2 = (const float*)d_in[12];
  const float* v2 = (const float*)d_in[13];
  const float* w3 = (const float*)d_in[14];
  const float* b3 = (const float*)d_in[15];
  const float* g3 = (const float*)d_in[16];
  const float* be3 = (const float*)d_in[17];
  const float* m3 = (const float*)d_in[18];
  const float* v3 = (const float*)d_in[19];
  const float* w4 = (const float*)d_in[20];
  const float* b4 = (const float*)d_in[21];

  char* ws = (char*)d_ws;
  float* cost = (float*)ws;                         // 200*128*256 f32 = 26.2 MB
  float* o1 = (float*)(ws + 26214400);              // 64*128*256  = 8.39 MB
  float* o2 = (float*)(ws + 26214400 + 8388608);    // 32*128*256  = 4.19 MB
  float* o3 = (float*)(ws + 26214400 + 8388608 + 4194304);  // 8*128*256
  float* o4 = (float*)d_out;                        // 1*128*256

  // 1. cost volume: [200][128][256]
  cost_volume_kernel<<<dim3(8, HH), 256, 0, stream>>>(left, right, cost);

  // 2. conv1 200->64 + BN + ReLU
  conv3x3_kernel<200, 8, true><<<dim3(WW / 64, HH / 16, 64 / 8), dim3(16, 16),
                                 0, stream>>>(cost, w1, b1, g1, be1, m1, v1, o1);
  // 3. conv2 64->32 + BN + ReLU
  conv3x3_kernel<64, 8, true><<<dim3(WW / 64, HH / 16, 32 / 8), dim3(16, 16),
                                0, stream>>>(o1, w2, b2, g2, be2, m2, v2, o2);
  // 4. conv3 32->8 + BN + ReLU
  conv3x3_kernel<32, 8, true><<<dim3(WW / 64, HH / 16, 1), dim3(16, 16), 0,
                                stream>>>(o2, w3, b3, g3, be3, m3, v3, o3);
  // 5. conv4 8->1 (bias only)
  conv3x3_kernel<8, 1, false><<<dim3(WW / 64, HH / 16, 1), dim3(16, 16), 0,
                                stream>>>(o3, w4, b4, nullptr, nullptr, nullptr,
                                          nullptr, o4);
}

// Round 2
// 276.306 us; speedup vs baseline: 2.5909x; 2.5909x over previous
//
#include <hip/hip_runtime.h>

#define HH 128
#define WW 256
#define CV_C 32
#define DISP 200
#define HW (HH * WW)

typedef __attribute__((ext_vector_type(4))) float f32x4;
typedef __attribute__((ext_vector_type(8))) short bf16x8;

__device__ inline unsigned short f2bf(float f) {
  unsigned int u = __float_as_uint(f);
  u = (u + 0x7FFFu + ((u >> 16) & 1u)) >> 16;  // RNE
  return (unsigned short)u;
}

// ---------------------------------------------------------------------------
// Cost volume (unchanged, known-good): cost[d,y,x] = sum_c L[c,y,x]*R[c,y,x+d-200]
// ---------------------------------------------------------------------------
__global__ __launch_bounds__(256) void cost_volume_kernel(
    const float* __restrict__ left, const float* __restrict__ right,
    float* __restrict__ cost) {
  __shared__ float rsh[CV_C][WW];
  const int x = threadIdx.x;
  const int y = blockIdx.y;
  const int d0 = blockIdx.x * 25;

  float lreg[CV_C];
#pragma unroll
  for (int c = 0; c < CV_C; ++c) {
    rsh[c][x] = right[(c * HH + y) * WW + x];
    lreg[c] = left[(c * HH + y) * WW + x];
  }
  __syncthreads();

  for (int dd = 0; dd < 25; ++dd) {
    const int d = d0 + dd;
    const int xi = x + d - DISP;
    float acc = 0.f;
    if (xi >= 0) {
#pragma unroll
      for (int c = 0; c < CV_C; ++c) acc += lreg[c] * rsh[c][xi];
    }
    cost[(d * HH + y) * WW + x] = acc;
  }
}

// ---------------------------------------------------------------------------
// Transpose+convert: cost f32 [200][128][256] -> cost_t bf16 [128][256][224]
// (d >= 200 zero-padded so conv1's K-loop needs no edge handling)
// ---------------------------------------------------------------------------
__global__ __launch_bounds__(256) void transpose_cost_kernel(
    const float* __restrict__ cost, unsigned short* __restrict__ cost_t) {
  __shared__ unsigned short t[64][232];  // 29.7 KB, padded stride
  const int y = blockIdx.y;
  const int x0 = blockIdx.x * 64;
  const int tid = threadIdx.x;
  const int xx = tid & 63;
  const int dq = tid >> 6;  // 0..3
  for (int i = 0; i < 56; ++i) {
    const int d = dq * 56 + i;  // covers 0..223
    float v = (d < DISP) ? cost[(d * HH + y) * WW + x0 + xx] : 0.f;
    t[xx][d] = f2bf(v);
  }
  __syncthreads();
  const int x = tid >> 2;
  const int q = tid & 3;
  for (int tc = 0; tc < 7; ++tc) {
    const int dblk = q * 7 + tc;  // 0..27
    bf16x8 v = *reinterpret_cast<const bf16x8*>(&t[x][dblk * 8]);
    *reinterpret_cast<bf16x8*>(&cost_t[(y * WW + x0 + x) * 224 + dblk * 8]) = v;
  }
}

// ---------------------------------------------------------------------------
// Weight pack: w1 f32 [64][200][3][3] -> pw bf16 [7][9][4][64][8]
// pw[chunk][pos][kg][n][j] = w1[n][chunk*32+kg*8+j][pos/3][pos%3] (0 if ci>=200)
// ---------------------------------------------------------------------------
__global__ __launch_bounds__(256) void pack_w1_kernel(
    const float* __restrict__ w1, unsigned short* __restrict__ pw) {
  const int idx = blockIdx.x * 256 + threadIdx.x;  // 129024 total
  const int j = idx & 7;
  const int n = (idx >> 3) & 63;
  const int kg = (idx >> 9) & 3;
  const int cp = idx >> 11;
  const int pos = cp % 9;
  const int chunk = cp / 9;
  const int ci = chunk * 32 + kg * 8 + j;
  float v = 0.f;
  if (ci < 200) v = w1[(n * 200 + ci) * 9 + pos];
  pw[idx] = f2bf(v);
}

// ---------------------------------------------------------------------------
// conv1 as implicit GEMM, bf16 MFMA 16x16x32.
// Block: 256 thr = 4 waves (2x2), output tile 64 px (x) x 64 couts at fixed y.
// K = 224 ci (zero-padded) x 9 positions, ci in 7 chunks of 32.
// A staged in LDS [3 rows][66 x][40 ci-pad] bf16 (80B stride: only 2-way bank
// conflicts, free). B fragments read straight from packed weights (L2, 258KB).
// ---------------------------------------------------------------------------
__global__ __launch_bounds__(256) void conv1_mfma_kernel(
    const unsigned short* __restrict__ cost_t,  // [128][256][224]
    const unsigned short* __restrict__ pw,      // [7][9][4][64][8]
    const float* __restrict__ bias, const float* __restrict__ gam,
    const float* __restrict__ bet, const float* __restrict__ mean,
    const float* __restrict__ var, float* __restrict__ out) {  // [64][128][256]
  __shared__ unsigned short a_sh[3 * 66 * 40];  // 15840 B
  const int tid = threadIdx.x;
  const int lane = tid & 63;
  const int w = tid >> 6;
  const int y = blockIdx.y;
  const int x0 = blockIdx.x * 64;
  const int m0 = (w >> 1) * 32;  // pixel offset within tile
  const int n0 = (w & 1) * 32;   // cout offset within tile
  const int col = lane & 15;
  const int kg = lane >> 4;

  f32x4 acc[2][2];
#pragma unroll
  for (int i = 0; i < 2; ++i)
#pragma unroll
    for (int jj = 0; jj < 2; ++jj) acc[i][jj] = 0.f;

  const bf16x8* pwv = (const bf16x8*)pw;
  const bf16x8* av = (const bf16x8*)a_sh;

  for (int chunk = 0; chunk < 7; ++chunk) {
    // ---- stage A chunk: [3][66][32ci] from cost_t, bf16x8 per thread-iter ----
    for (int i = tid; i < 792; i += 256) {  // 3*66*4
      const int row = i / 264;
      const int rem = i % 264;
      const int xx = rem >> 2;
      const int q = rem & 3;
      const int gy = y + row - 1;
      const int gx = x0 - 1 + xx;
      bf16x8 v = {0, 0, 0, 0, 0, 0, 0, 0};
      if (gy >= 0 && gy < HH && gx >= 0 && gx < WW)
        v = *reinterpret_cast<const bf16x8*>(
            &cost_t[(gy * WW + gx) * 224 + chunk * 32 + q * 8]);
      *reinterpret_cast<bf16x8*>(&a_sh[(row * 66 + xx) * 40 + q * 8]) = v;
    }
    __syncthreads();

#pragma unroll
    for (int pos = 0; pos < 9; ++pos) {
      const int ky = pos / 3;
      const int kx = pos % 3;
      const int bbase = ((chunk * 9 + pos) * 4 + kg) * 64;
      const bf16x8 b0v = pwv[bbase + n0 + col];
      const bf16x8 b1v = pwv[bbase + n0 + 16 + col];
      const bf16x8 a0v = av[(ky * 66 + m0 + col + kx) * 5 + kg];
      const bf16x8 a1v = av[(ky * 66 + m0 + 16 + col + kx) * 5 + kg];
      acc[0][0] = __builtin_amdgcn_mfma_f32_16x16x32_bf16(a0v, b0v, acc[0][0], 0, 0, 0);
      acc[0][1] = __builtin_amdgcn_mfma_f32_16x16x32_bf16(a0v, b1v, acc[0][1], 0, 0, 0);
      acc[1][0] = __builtin_amdgcn_mfma_f32_16x16x32_bf16(a1v, b0v, acc[1][0], 0, 0, 0);
      acc[1][1] = __builtin_amdgcn_mfma_f32_16x16x32_bf16(a1v, b1v, acc[1][1], 0, 0, 0);
    }
    __syncthreads();
  }

  // ---- epilogue: bias + BN + ReLU, f32 out [c][y][x] ----
  const int rbase = (lane >> 4) * 4;
#pragma unroll
  for (int nf = 0; nf < 2; ++nf) {
    const int c = n0 + nf * 16 + col;
    const float inv = rsqrtf(var[c] + 1e-5f);
    const float sc = gam[c] * inv;
    const float sh = bet[c] - mean[c] * sc;
    const float bb = bias[c];
#pragma unroll
    for (int mf = 0; mf < 2; ++mf) {
#pragma unroll
      for (int r = 0; r < 4; ++r) {
        const int m = m0 + mf * 16 + rbase + r;
        float vv = (acc[mf][nf][r] + bb) * sc + sh;
        vv = fmaxf(vv, 0.f);
        out[c * HW + y * WW + x0 + m] = vv;
      }
    }
  }
}

// ---------------------------------------------------------------------------
// Direct 3x3 conv + optional BN/ReLU (round-1 kernel, NCO now tunable for grid)
// ---------------------------------------------------------------------------
template <int CIN, int NCO, bool BN_RELU>
__global__ __launch_bounds__(256) void conv3x3_kernel(
    const float* __restrict__ in, const float* __restrict__ wgt,
    const float* __restrict__ bias, const float* __restrict__ gam,
    const float* __restrict__ bet, const float* __restrict__ mean,
    const float* __restrict__ var, float* __restrict__ out) {
  constexpr int TW = 64;
  constexpr int TH = 16;
  constexpr int CCH = 8;
  constexpr int HS = TW + 2;
  constexpr int PS = 68;

  __shared__ float ish[CCH][TH + 2][PS];
  __shared__ float wsh[CCH][9][NCO];

  const int tx = threadIdx.x;
  const int ty = threadIdx.y;
  const int tid = ty * 16 + tx;
  const int x0 = blockIdx.x * TW;
  const int y0 = blockIdx.y * TH;
  const int co0 = blockIdx.z * NCO;

  float acc[NCO][4];
#pragma unroll
  for (int co = 0; co < NCO; ++co)
#pragma unroll
    for (int p = 0; p < 4; ++p) acc[co][p] = 0.f;

  for (int ci0 = 0; ci0 < CIN; ci0 += CCH) {
    constexpr int NELEM = CCH * (TH + 2) * HS;
    for (int i = tid; i < NELEM; i += 256) {
      const int ci = i / ((TH + 2) * HS);
      const int rem = i % ((TH + 2) * HS);
      const int yy = rem / HS;
      const int xx = rem % HS;
      const int gy = y0 + yy - 1;
      const int gx = x0 + xx - 1;
      float v = 0.f;
      if (gy >= 0 && gy < HH && gx >= 0 && gx < WW)
        v = in[((ci0 + ci) * HH + gy) * WW + gx];
      ish[ci][yy][xx] = v;
    }
    constexpr int NWEL = CCH * 9 * NCO;
    for (int i = tid; i < NWEL; i += 256) {
      const int ci = i / (9 * NCO);
      const int rem = i % (9 * NCO);
      const int k = rem / NCO;
      const int co = rem % NCO;
      wsh[ci][k][co] = wgt[((co0 + co) * CIN + ci0 + ci) * 9 + k];
    }
    __syncthreads();

#pragma unroll
    for (int ci = 0; ci < CCH; ++ci) {
#pragma unroll
      for (int ky = 0; ky < 3; ++ky) {
        const float4 v4 =
            *reinterpret_cast<const float4*>(&ish[ci][ty + ky][4 * tx]);
        const float2 v2 =
            *reinterpret_cast<const float2*>(&ish[ci][ty + ky][4 * tx + 4]);
        const float iv[6] = {v4.x, v4.y, v4.z, v4.w, v2.x, v2.y};
#pragma unroll
        for (int kx = 0; kx < 3; ++kx) {
#pragma unroll
          for (int co = 0; co < NCO; ++co) {
            const float wv = wsh[ci][ky * 3 + kx][co];
            acc[co][0] += iv[kx + 0] * wv;
            acc[co][1] += iv[kx + 1] * wv;
            acc[co][2] += iv[kx + 2] * wv;
            acc[co][3] += iv[kx + 3] * wv;
          }
        }
      }
    }
    __syncthreads();
  }

  const int oy = y0 + ty;
  const int ox = x0 + 4 * tx;
#pragma unroll
  for (int co = 0; co < NCO; ++co) {
    const int c = co0 + co;
    const float b = bias[c];
    float sc = 1.f, sh = 0.f;
    if (BN_RELU) {
      const float inv = rsqrtf(var[c] + 1e-5f);
      sc = gam[c] * inv;
      sh = bet[c] - mean[c] * sc;
    }
    float4 r;
    float* rp = &r.x;
#pragma unroll
    for (int p = 0; p < 4; ++p) {
      float v = acc[co][p] + b;
      if (BN_RELU) {
        v = v * sc + sh;
        v = fmaxf(v, 0.f);
      }
      rp[p] = v;
    }
    *reinterpret_cast<float4*>(&out[(c * HH + oy) * WW + ox]) = r;
  }
}

// ---------------------------------------------------------------------------
extern "C" void kernel_launch(void* const* d_in, const int* in_sizes, int n_in,
                              void* d_out, int out_size, void* d_ws,
                              size_t ws_size, hipStream_t stream) {
  const float* left = (const float*)d_in[0];
  const float* right = (const float*)d_in[1];
  const float* w1 = (const float*)d_in[2];
  const float* b1 = (const float*)d_in[3];
  const float* g1 = (const float*)d_in[4];
  const float* be1 = (const float*)d_in[5];
  const float* m1 = (const float*)d_in[6];
  const float* v1 = (const float*)d_in[7];
  const float* w2 = (const float*)d_in[8];
  const float* b2 = (const float*)d_in[9];
  const float* g2 = (const float*)d_in[10];
  const float* be2 = (const float*)d_in[11];
  const float* m2 = (const float*)d_in[12];
  const float* v2 = (const float*)d_in[13];
  const float* w3 = (const float*)d_in[14];
  const float* b3 = (const float*)d_in[15];
  const float* g3 = (const float*)d_in[16];
  const float* be3 = (const float*)d_in[17];
  const float* m3 = (const float*)d_in[18];
  const float* v3 = (const float*)d_in[19];
  const float* w4 = (const float*)d_in[20];
  const float* b4 = (const float*)d_in[21];

  // Workspace layout (total 40,894,464 B == round-1 usage):
  //   [0, 14680064)            cost_t bf16 [128][256][224]
  //   [14680064, 40894464)     region: cost f32 (26.2MB) -- dead after
  //                            transpose; then reused as pw + o1 + o2 + o3
  char* ws = (char*)d_ws;
  unsigned short* cost_t = (unsigned short*)ws;
  char* region = ws + 14680064;
  float* cost = (float*)region;
  unsigned short* pw = (unsigned short*)region;        // 258048 B
  float* o1 = (float*)(region + 262144);               // 8388608 B
  float* o2 = (float*)(region + 262144 + 8388608);     // 4194304 B
  float* o3 = (float*)(region + 262144 + 12582912);    // 2097152 B
  float* o4 = (float*)d_out;

  cost_volume_kernel<<<dim3(8, HH), 256, 0, stream>>>(left, right, cost);
  transpose_cost_kernel<<<dim3(4, HH), 256, 0, stream>>>(cost, cost_t);
  // cost f32 dead from here; pack overwrites its head
  pack_w1_kernel<<<504, 256, 0, stream>>>(w1, pw);
  conv1_mfma_kernel<<<dim3(4, HH), 256, 0, stream>>>(cost_t, pw, b1, g1, be1,
                                                     m1, v1, o1);
  conv3x3_kernel<64, 4, true><<<dim3(4, 8, 8), dim3(16, 16), 0, stream>>>(
      o1, w2, b2, g2, be2, m2, v2, o2);
  conv3x3_kernel<32, 2, true><<<dim3(4, 8, 4), dim3(16, 16), 0, stream>>>(
      o2, w3, b3, g3, be3, m3, v3, o3);
  conv3x3_kernel<8, 1, false><<<dim3(4, 8, 1), dim3(16, 16), 0, stream>>>(
      o3, w4, b4, nullptr, nullptr, nullptr, nullptr, o4);
}

// Round 3
// 97.912 us; speedup vs baseline: 7.3115x; 2.8220x over previous
//
#include <hip/hip_runtime.h>

#define HH 128
#define WW 256
#define CV_C 32
#define DISP 200
#define HW (HH * WW)

typedef __attribute__((ext_vector_type(4))) float f32x4;
typedef __attribute__((ext_vector_type(8))) short bf16x8;

__device__ inline unsigned short f2bf(float f) {
  unsigned int u = __float_as_uint(f);
  u = (u + 0x7FFFu + ((u >> 16) & 1u)) >> 16;  // RNE
  return (unsigned short)u;
}

__device__ inline float bf2f(short s) {
  return __uint_as_float(((unsigned int)(unsigned short)s) << 16);
}

// ---------------------------------------------------------------------------
// Cost volume (known-good): cost[d,y,x] = sum_c L[c,y,x]*R[c,y,x+d-200]
// ---------------------------------------------------------------------------
__global__ __launch_bounds__(256) void cost_volume_kernel(
    const float* __restrict__ left, const float* __restrict__ right,
    float* __restrict__ cost) {
  __shared__ float rsh[CV_C][WW];
  const int x = threadIdx.x;
  const int y = blockIdx.y;
  const int d0 = blockIdx.x * 25;

  float lreg[CV_C];
#pragma unroll
  for (int c = 0; c < CV_C; ++c) {
    rsh[c][x] = right[(c * HH + y) * WW + x];
    lreg[c] = left[(c * HH + y) * WW + x];
  }
  __syncthreads();

  for (int dd = 0; dd < 25; ++dd) {
    const int d = d0 + dd;
    const int xi = x + d - DISP;
    float acc = 0.f;
    if (xi >= 0) {
#pragma unroll
      for (int c = 0; c < CV_C; ++c) acc += lreg[c] * rsh[c][xi];
    }
    cost[(d * HH + y) * WW + x] = acc;
  }
}

// ---------------------------------------------------------------------------
// Transpose+convert: cost f32 [200][128][256] -> cost_t bf16 [128][256][224]
// ---------------------------------------------------------------------------
__global__ __launch_bounds__(256) void transpose_cost_kernel(
    const float* __restrict__ cost, unsigned short* __restrict__ cost_t) {
  __shared__ unsigned short t[64][232];
  const int y = blockIdx.y;
  const int x0 = blockIdx.x * 64;
  const int tid = threadIdx.x;
  const int xx = tid & 63;
  const int dq = tid >> 6;
  for (int i = 0; i < 56; ++i) {
    const int d = dq * 56 + i;
    float v = (d < DISP) ? cost[(d * HH + y) * WW + x0 + xx] : 0.f;
    t[xx][d] = f2bf(v);
  }
  __syncthreads();
  const int x = tid >> 2;
  const int q = tid & 3;
  for (int tc = 0; tc < 7; ++tc) {
    const int dblk = q * 7 + tc;
    bf16x8 v = *reinterpret_cast<const bf16x8*>(&t[x][dblk * 8]);
    *reinterpret_cast<bf16x8*>(&cost_t[(y * WW + x0 + x) * 224 + dblk * 8]) = v;
  }
}

// ---------------------------------------------------------------------------
// Weight packs: pw[chunk][pos][kg][n][j] = w[n][ci_of(chunk,kg,j)][pos]
// ---------------------------------------------------------------------------
__global__ __launch_bounds__(256) void pack_w1_kernel(
    const float* __restrict__ w1, unsigned short* __restrict__ pw) {
  const int idx = blockIdx.x * 256 + threadIdx.x;  // 129024
  const int j = idx & 7;
  const int n = (idx >> 3) & 63;
  const int kg = (idx >> 9) & 3;
  const int cp = idx >> 11;
  const int pos = cp % 9;
  const int chunk = cp / 9;
  const int ci = chunk * 32 + kg * 8 + j;
  float v = 0.f;
  if (ci < 200) v = w1[(n * 200 + ci) * 9 + pos];
  pw[idx] = f2bf(v);
}

// pb2[pos 9][kc 2][kg 4][n 32][j 8]
__global__ __launch_bounds__(256) void pack_w2_kernel(
    const float* __restrict__ w2, unsigned short* __restrict__ pb) {
  const int idx = blockIdx.x * 256 + threadIdx.x;  // 18432
  const int j = idx & 7;
  const int n = (idx >> 3) & 31;
  const int kg = (idx >> 8) & 3;
  const int kc = (idx >> 10) & 1;
  const int pos = idx >> 11;
  const int ci = kc * 32 + kg * 8 + j;
  pb[idx] = f2bf(w2[(n * 64 + ci) * 9 + pos]);
}

// pb3[pos 9][kg 4][n 16 (8 real)][j 8]
__global__ __launch_bounds__(256) void pack_w3_kernel(
    const float* __restrict__ w3, unsigned short* __restrict__ pb) {
  const int idx = blockIdx.x * 256 + threadIdx.x;  // 4608
  const int j = idx & 7;
  const int n = (idx >> 3) & 15;
  const int kg = (idx >> 7) & 3;
  const int pos = idx >> 9;
  const int ci = kg * 8 + j;
  float v = 0.f;
  if (n < 8) v = w3[(n * 32 + ci) * 9 + pos];
  pb[idx] = f2bf(v);
}

// ---------------------------------------------------------------------------
// conv1: implicit GEMM bf16 MFMA. In: cost_t [128][256][224]. Out: o1_t NHWC
// bf16 [128][256][64].
// ---------------------------------------------------------------------------
__global__ __launch_bounds__(256) void conv1_mfma_kernel(
    const unsigned short* __restrict__ cost_t,
    const unsigned short* __restrict__ pw,  // [7][9][4][64][8]
    const float* __restrict__ bias, const float* __restrict__ gam,
    const float* __restrict__ bet, const float* __restrict__ mean,
    const float* __restrict__ var, unsigned short* __restrict__ out_t) {
  __shared__ unsigned short a_sh[3 * 66 * 40];  // 15840 B
  const int tid = threadIdx.x;
  const int lane = tid & 63;
  const int w = tid >> 6;
  const int y = blockIdx.y;
  const int x0 = blockIdx.x * 64;
  const int m0 = (w >> 1) * 32;
  const int n0 = (w & 1) * 32;
  const int col = lane & 15;
  const int kg = lane >> 4;

  f32x4 acc[2][2];
#pragma unroll
  for (int i = 0; i < 2; ++i)
#pragma unroll
    for (int jj = 0; jj < 2; ++jj) acc[i][jj] = 0.f;

  const bf16x8* pwv = (const bf16x8*)pw;
  const bf16x8* av = (const bf16x8*)a_sh;

  for (int chunk = 0; chunk < 7; ++chunk) {
    for (int i = tid; i < 792; i += 256) {  // 3*66*4
      const int row = i / 264;
      const int rem = i % 264;
      const int xx = rem >> 2;
      const int q = rem & 3;
      const int gy = y + row - 1;
      const int gx = x0 - 1 + xx;
      bf16x8 v = {0, 0, 0, 0, 0, 0, 0, 0};
      if (gy >= 0 && gy < HH && gx >= 0 && gx < WW)
        v = *reinterpret_cast<const bf16x8*>(
            &cost_t[(gy * WW + gx) * 224 + chunk * 32 + q * 8]);
      *reinterpret_cast<bf16x8*>(&a_sh[(row * 66 + xx) * 40 + q * 8]) = v;
    }
    __syncthreads();

#pragma unroll
    for (int pos = 0; pos < 9; ++pos) {
      const int ky = pos / 3;
      const int kx = pos % 3;
      const int bbase = ((chunk * 9 + pos) * 4 + kg) * 64;
      const bf16x8 b0v = pwv[bbase + n0 + col];
      const bf16x8 b1v = pwv[bbase + n0 + 16 + col];
      const bf16x8 a0v = av[(ky * 66 + m0 + col + kx) * 5 + kg];
      const bf16x8 a1v = av[(ky * 66 + m0 + 16 + col + kx) * 5 + kg];
      acc[0][0] = __builtin_amdgcn_mfma_f32_16x16x32_bf16(a0v, b0v, acc[0][0], 0, 0, 0);
      acc[0][1] = __builtin_amdgcn_mfma_f32_16x16x32_bf16(a0v, b1v, acc[0][1], 0, 0, 0);
      acc[1][0] = __builtin_amdgcn_mfma_f32_16x16x32_bf16(a1v, b0v, acc[1][0], 0, 0, 0);
      acc[1][1] = __builtin_amdgcn_mfma_f32_16x16x32_bf16(a1v, b1v, acc[1][1], 0, 0, 0);
    }
    __syncthreads();
  }

  const int rbase = (lane >> 4) * 4;
#pragma unroll
  for (int nf = 0; nf < 2; ++nf) {
    const int c = n0 + nf * 16 + col;
    const float inv = rsqrtf(var[c] + 1e-5f);
    const float sc = gam[c] * inv;
    const float sh = bet[c] - mean[c] * sc;
    const float bb = bias[c];
#pragma unroll
    for (int mf = 0; mf < 2; ++mf) {
#pragma unroll
      for (int r = 0; r < 4; ++r) {
        const int m = m0 + mf * 16 + rbase + r;
        float vv = (acc[mf][nf][r] + bb) * sc + sh;
        vv = fmaxf(vv, 0.f);
        out_t[((y * WW + x0 + m) << 6) + c] = f2bf(vv);
      }
    }
  }
}

// ---------------------------------------------------------------------------
// conv2: 64->32, NHWC bf16 in/out. 4 waves (2M x 2N), tile 64px x 32co.
// A-tile [3][66][64] bf16 in LDS, XOR-swizzled (row stride 128B).
// ---------------------------------------------------------------------------
__global__ __launch_bounds__(256) void conv2_mfma_kernel(
    const unsigned short* __restrict__ in_t,  // [128][256][64]
    const unsigned short* __restrict__ pb,    // [9][2][4][32][8]
    const float* __restrict__ bias, const float* __restrict__ gam,
    const float* __restrict__ bet, const float* __restrict__ mean,
    const float* __restrict__ var, unsigned short* __restrict__ out_t) {
  __shared__ unsigned short a_sh[3 * 66 * 64];  // 25344 B
  char* const ab = (char*)a_sh;
  const int tid = threadIdx.x;
  const int lane = tid & 63;
  const int w = tid >> 6;
  const int y = blockIdx.y;
  const int x0 = blockIdx.x * 64;
  const int m0 = (w >> 1) * 32;
  const int n0 = (w & 1) * 16;
  const int col = lane & 15;
  const int kg = lane >> 4;

  f32x4 acc[2];
  acc[0] = 0.f;
  acc[1] = 0.f;

  for (int i = tid; i < 1584; i += 256) {  // 3*66*8
    const int r = i >> 3;
    const int q = i & 7;
    const int rowy = r / 66;
    const int xx = r % 66;
    const int gy = y + rowy - 1;
    const int gx = x0 - 1 + xx;
    bf16x8 v = {0, 0, 0, 0, 0, 0, 0, 0};
    if (gy >= 0 && gy < HH && gx >= 0 && gx < WW)
      v = *reinterpret_cast<const bf16x8*>(&in_t[((gy * WW + gx) << 6) + q * 8]);
    const int byte = ((r << 7) + (q << 4)) ^ ((r & 7) << 4);
    *reinterpret_cast<bf16x8*>(ab + byte) = v;
  }
  __syncthreads();

  const bf16x8* pbv = (const bf16x8*)pb;
#pragma unroll
  for (int pos = 0; pos < 9; ++pos) {
    const int ky = pos / 3;
    const int kx = pos % 3;
#pragma unroll
    for (int kc = 0; kc < 2; ++kc) {
      const bf16x8 bv = pbv[((pos * 2 + kc) * 4 + kg) * 32 + n0 + col];
#pragma unroll
      for (int mf = 0; mf < 2; ++mf) {
        const int r = ky * 66 + m0 + mf * 16 + col + kx;
        const int byte = ((r << 7) + (kc << 6) + (kg << 4)) ^ ((r & 7) << 4);
        const bf16x8 av = *reinterpret_cast<const bf16x8*>(ab + byte);
        acc[mf] = __builtin_amdgcn_mfma_f32_16x16x32_bf16(av, bv, acc[mf], 0, 0, 0);
      }
    }
  }

  const int c = n0 + col;
  const float inv = rsqrtf(var[c] + 1e-5f);
  const float sc = gam[c] * inv;
  const float sh = bet[c] - mean[c] * sc;
  const float bb = bias[c];
  const int rbase = kg * 4;
#pragma unroll
  for (int mf = 0; mf < 2; ++mf) {
#pragma unroll
    for (int r = 0; r < 4; ++r) {
      const int m = m0 + mf * 16 + rbase + r;
      float vv = (acc[mf][r] + bb) * sc + sh;
      vv = fmaxf(vv, 0.f);
      out_t[((y * WW + x0 + m) << 5) + c] = f2bf(vv);
    }
  }
}

// ---------------------------------------------------------------------------
// conv3: 32->8 (N padded to 16), NHWC bf16. 4 waves x 16px, tile 64px.
// A-tile [3][66][32] bf16, XOR-swizzled (row stride 64B).
// ---------------------------------------------------------------------------
__global__ __launch_bounds__(256) void conv3_mfma_kernel(
    const unsigned short* __restrict__ in_t,  // [128][256][32]
    const unsigned short* __restrict__ pb,    // [9][4][16][8]
    const float* __restrict__ bias, const float* __restrict__ gam,
    const float* __restrict__ bet, const float* __restrict__ mean,
    const float* __restrict__ var, unsigned short* __restrict__ out_t) {
  __shared__ unsigned short a_sh[3 * 66 * 32];  // 12672 B
  char* const ab = (char*)a_sh;
  const int tid = threadIdx.x;
  const int lane = tid & 63;
  const int w = tid >> 6;
  const int y = blockIdx.y;
  const int x0 = blockIdx.x * 64;
  const int m0 = w * 16;
  const int col = lane & 15;
  const int kg = lane >> 4;

  f32x4 acc = 0.f;

  for (int i = tid; i < 792; i += 256) {  // 3*66*4
    const int r = i >> 2;
    const int q = i & 3;
    const int rowy = r / 66;
    const int xx = r % 66;
    const int gy = y + rowy - 1;
    const int gx = x0 - 1 + xx;
    bf16x8 v = {0, 0, 0, 0, 0, 0, 0, 0};
    if (gy >= 0 && gy < HH && gx >= 0 && gx < WW)
      v = *reinterpret_cast<const bf16x8*>(&in_t[((gy * WW + gx) << 5) + q * 8]);
    const int byte = ((r << 6) + (q << 4)) ^ ((r & 3) << 4);
    *reinterpret_cast<bf16x8*>(ab + byte) = v;
  }
  __syncthreads();

  const bf16x8* pbv = (const bf16x8*)pb;
#pragma unroll
  for (int pos = 0; pos < 9; ++pos) {
    const int ky = pos / 3;
    const int kx = pos % 3;
    const bf16x8 bv = pbv[(pos * 4 + kg) * 16 + col];
    const int r = ky * 66 + m0 + col + kx;
    const int byte = ((r << 6) + (kg << 4)) ^ ((r & 3) << 4);
    const bf16x8 av = *reinterpret_cast<const bf16x8*>(ab + byte);
    acc = __builtin_amdgcn_mfma_f32_16x16x32_bf16(av, bv, acc, 0, 0, 0);
  }

  if (col < 8) {
    const int c = col;
    const float inv = rsqrtf(var[c] + 1e-5f);
    const float sc = gam[c] * inv;
    const float sh = bet[c] - mean[c] * sc;
    const float bb = bias[c];
    const int rbase = kg * 4;
#pragma unroll
    for (int r = 0; r < 4; ++r) {
      const int m = m0 + rbase + r;
      float vv = (acc[r] + bb) * sc + sh;
      vv = fmaxf(vv, 0.f);
      out_t[((y * WW + x0 + m) << 3) + c] = f2bf(vv);
    }
  }
}

// ---------------------------------------------------------------------------
// conv4: 8->1, per-pixel direct. in_t NHWC bf16 [128][256][8] (L2-resident).
// ---------------------------------------------------------------------------
__global__ __launch_bounds__(256) void conv4_kernel(
    const unsigned short* __restrict__ in_t, const float* __restrict__ w4,
    const float* __restrict__ b4, float* __restrict__ out) {
  const int p = blockIdx.x * 256 + threadIdx.x;
  const int y = p >> 8;
  const int x = p & 255;

  float wr[3][3][8];
#pragma unroll
  for (int ci = 0; ci < 8; ++ci)
#pragma unroll
    for (int ky = 0; ky < 3; ++ky)
#pragma unroll
      for (int kx = 0; kx < 3; ++kx) wr[ky][kx][ci] = w4[(ci * 3 + ky) * 3 + kx];

  float acc = b4[0];
#pragma unroll
  for (int ky = 0; ky < 3; ++ky) {
    const int gy = y + ky - 1;
    if (gy < 0 || gy >= HH) continue;
#pragma unroll
    for (int kx = 0; kx < 3; ++kx) {
      const int gx = x + kx - 1;
      if (gx < 0 || gx >= WW) continue;
      const bf16x8 v =
          *reinterpret_cast<const bf16x8*>(&in_t[((gy << 8) + gx) << 3]);
#pragma unroll
      for (int ci = 0; ci < 8; ++ci) acc += bf2f(v[ci]) * wr[ky][kx][ci];
    }
  }
  out[p] = acc;
}

// ---------------------------------------------------------------------------
extern "C" void kernel_launch(void* const* d_in, const int* in_sizes, int n_in,
                              void* d_out, int out_size, void* d_ws,
                              size_t ws_size, hipStream_t stream) {
  const float* left = (const float*)d_in[0];
  const float* right = (const float*)d_in[1];
  const float* w1 = (const float*)d_in[2];
  const float* b1 = (const float*)d_in[3];
  const float* g1 = (const float*)d_in[4];
  const float* be1 = (const float*)d_in[5];
  const float* m1 = (const float*)d_in[6];
  const float* v1 = (const float*)d_in[7];
  const float* w2 = (const float*)d_in[8];
  const float* b2 = (const float*)d_in[9];
  const float* g2 = (const float*)d_in[10];
  const float* be2 = (const float*)d_in[11];
  const float* m2 = (const float*)d_in[12];
  const float* v2 = (const float*)d_in[13];
  const float* w3 = (const float*)d_in[14];
  const float* b3 = (const float*)d_in[15];
  const float* g3 = (const float*)d_in[16];
  const float* be3 = (const float*)d_in[17];
  const float* m3 = (const float*)d_in[18];
  const float* v3 = (const float*)d_in[19];
  const float* w4 = (const float*)d_in[20];
  const float* b4 = (const float*)d_in[21];

  // Workspace (40,894,464 B total, same as round 1/2):
  //  [0, 14680064)          cost_t bf16 [128][256][224]
  //  [14680064, 40894464)   cost f32 (26.2MB, dead after transpose), then:
  //      +0        pw1  (258048, reserve 262144)
  //      +262144   pb2  (36864, reserve 65536)
  //      +327680   pb3  (9216, reserve 65536)
  //      +393216   o1_t bf16 [128][256][64]  (4194304)
  //      +4587520  o2_t bf16 [128][256][32]  (2097152)
  //      +6684672  o3_t bf16 [128][256][8]   (524288)
  char* ws = (char*)d_ws;
  unsigned short* cost_t = (unsigned short*)ws;
  char* region = ws + 14680064;
  float* cost = (float*)region;
  unsigned short* pw1 = (unsigned short*)(region + 0);
  unsigned short* pb2 = (unsigned short*)(region + 262144);
  unsigned short* pb3 = (unsigned short*)(region + 327680);
  unsigned short* o1t = (unsigned short*)(region + 393216);
  unsigned short* o2t = (unsigned short*)(region + 4587520);
  unsigned short* o3t = (unsigned short*)(region + 6684672);
  float* o4 = (float*)d_out;

  cost_volume_kernel<<<dim3(8, HH), 256, 0, stream>>>(left, right, cost);
  transpose_cost_kernel<<<dim3(4, HH), 256, 0, stream>>>(cost, cost_t);
  // cost f32 dead from here; packs overwrite its head
  pack_w1_kernel<<<504, 256, 0, stream>>>(w1, pw1);
  pack_w2_kernel<<<72, 256, 0, stream>>>(w2, pb2);
  pack_w3_kernel<<<18, 256, 0, stream>>>(w3, pb3);
  conv1_mfma_kernel<<<dim3(4, HH), 256, 0, stream>>>(cost_t, pw1, b1, g1, be1,
                                                     m1, v1, o1t);
  conv2_mfma_kernel<<<dim3(4, HH), 256, 0, stream>>>(o1t, pb2, b2, g2, be2, m2,
                                                     v2, o2t);
  conv3_mfma_kernel<<<dim3(4, HH), 256, 0, stream>>>(o2t, pb3, b3, g3, be3, m3,
                                                     v3, o3t);
  conv4_kernel<<<128, 256, 0, stream>>>(o3t, w4, b4, o4);
}

// Round 4
// 60.654 us; speedup vs baseline: 11.8028x; 1.6143x over previous
//
#include <hip/hip_runtime.h>

#define HH 128
#define WW 256
#define CV_C 32
#define DISP 200
#define HW (HH * WW)

typedef __attribute__((ext_vector_type(4))) float f32x4;
typedef __attribute__((ext_vector_type(8))) short bf16x8;

__device__ inline unsigned short f2bf(float f) {
  unsigned int u = __float_as_uint(f);
  u = (u + 0x7FFFu + ((u >> 16) & 1u)) >> 16;  // RNE
  return (unsigned short)u;
}

__device__ inline float bf2f(short s) {
  return __uint_as_float(((unsigned int)(unsigned short)s) << 16);
}

// ---------------------------------------------------------------------------
// Fused cost volume via MFMA band-matmul -> cost_t bf16 [128][256][224].
// cost[d,y,x] = sum_c L[c,y,x]*R[c,y,x+d-200] = corr(x, x') with x'=x+d-200,
// i.e. the band x-x' in [1,200] of the per-row Gram matrix R(x') x L(x).
// Block: 256 thr = 4 waves; wave w owns x-tile [x0+16w, x0+16w+15].
// Per wave: 14 x'-tiles x 2 MFMA (L split hi/lo for f32-grade accuracy).
// Scatter into zeroed c_sh[64][224], then coalesced bf16x8 writeout.
// ---------------------------------------------------------------------------
__global__ __launch_bounds__(256) void cost_volume_mfma_kernel(
    const float* __restrict__ left, const float* __restrict__ right,
    unsigned short* __restrict__ cost_t) {
  __shared__ unsigned short r_sh[272][40];  // 21760 B  (x' = x0-208 .. x0+63)
  __shared__ unsigned short l_hi[64][40];   // 5120 B
  __shared__ unsigned short l_lo[64][40];   // 5120 B
  __shared__ unsigned short c_sh[64][224];  // 28672 B   (total 60672 B)
  const int tid = threadIdx.x;
  const int lane = tid & 63;
  const int w = tid >> 6;
  const int y = blockIdx.y;
  const int x0 = blockIdx.x * 64;
  const int col = lane & 15;
  const int kg = lane >> 4;

  // ---- stage L with hi/lo split (wave w handles c = w, w+4, ...) ----
  for (int c = w; c < CV_C; c += 4) {
    const float v = left[(c * HH + y) * WW + x0 + lane];
    const unsigned short h = f2bf(v);
    l_hi[lane][c] = h;
    l_lo[lane][c] = f2bf(v - bf2f(h));
  }
  // ---- stage R (bf16), zero left of image border ----
  for (int c = w; c < CV_C; c += 4) {
    for (int pb = 0; pb < 320; pb += 64) {
      const int p = pb + lane;
      if (p < 272) {
        const int xp = x0 - 208 + p;
        float v = (xp >= 0) ? right[(c * HH + y) * WW + xp] : 0.f;
        r_sh[p][c] = f2bf(v);
      }
    }
  }
  // ---- zero the output staging tile (d in [200,224) must stay 0) ----
  {
    bf16x8 z = {0, 0, 0, 0, 0, 0, 0, 0};
    bf16x8* cz = (bf16x8*)c_sh;
#pragma unroll
    for (int k = 0; k < 7; ++k) cz[k * 256 + tid] = z;
  }
  __syncthreads();

  // B operand (L, output cols = x): fixed per wave.
  const bf16x8 b_hi = *(const bf16x8*)&l_hi[16 * w + col][kg * 8];
  const bf16x8 b_lo = *(const bf16x8*)&l_lo[16 * w + col][kg * 8];

  for (int t = 0; t < 14; ++t) {
    const int pb = 16 * (w - t) + 208;  // r_sh row base, in [0,256]
    const bf16x8 a_r = *(const bf16x8*)&r_sh[pb + col][kg * 8];
    f32x4 acc = {0.f, 0.f, 0.f, 0.f};
    acc = __builtin_amdgcn_mfma_f32_16x16x32_bf16(a_r, b_hi, acc, 0, 0, 0);
    acc = __builtin_amdgcn_mfma_f32_16x16x32_bf16(a_r, b_lo, acc, 0, 0, 0);
    // C[m][n]: m = x'-in-tile = kg*4+r, n = x-in-tile = col.
    // d = x' - x + 200 = kg*4+r - col - 16t + 200
#pragma unroll
    for (int r = 0; r < 4; ++r) {
      const int d = 200 - 16 * t + kg * 4 + r - col;
      if (d >= 0 && d < DISP) c_sh[16 * w + col][d] = f2bf(acc[r]);
    }
  }
  __syncthreads();

  // ---- coalesced writeout: 64 x-rows x 224 d  ----
#pragma unroll
  for (int k = 0; k < 7; ++k) {
    const int s = k * 256 + tid;  // 0..1791 vec slots
    const int x = s / 28;
    const int dv = s - x * 28;
    *reinterpret_cast<bf16x8*>(&cost_t[(y * WW + x0 + x) * 224 + dv * 8]) =
        *reinterpret_cast<const bf16x8*>(&c_sh[x][dv * 8]);
  }
}

// ---------------------------------------------------------------------------
// All weight packs in one kernel (blocks 0..503 w1, 504..575 w2, 576..593 w3)
// ---------------------------------------------------------------------------
__global__ __launch_bounds__(256) void pack_all_kernel(
    const float* __restrict__ w1, const float* __restrict__ w2,
    const float* __restrict__ w3, unsigned short* __restrict__ pw1,
    unsigned short* __restrict__ pb2, unsigned short* __restrict__ pb3) {
  const int b = blockIdx.x;
  if (b < 504) {  // pw1[chunk 7][pos 9][kg 4][n 64][j 8]
    const int idx = b * 256 + threadIdx.x;
    const int j = idx & 7;
    const int n = (idx >> 3) & 63;
    const int kg = (idx >> 9) & 3;
    const int cp = idx >> 11;
    const int pos = cp % 9;
    const int chunk = cp / 9;
    const int ci = chunk * 32 + kg * 8 + j;
    float v = 0.f;
    if (ci < 200) v = w1[(n * 200 + ci) * 9 + pos];
    pw1[idx] = f2bf(v);
  } else if (b < 576) {  // pb2[pos 9][kc 2][kg 4][n 32][j 8]
    const int idx = (b - 504) * 256 + threadIdx.x;
    const int j = idx & 7;
    const int n = (idx >> 3) & 31;
    const int kg = (idx >> 8) & 3;
    const int kc = (idx >> 10) & 1;
    const int pos = idx >> 11;
    const int ci = kc * 32 + kg * 8 + j;
    pb2[idx] = f2bf(w2[(n * 64 + ci) * 9 + pos]);
  } else {  // pb3[pos 9][kg 4][n 16(8 real)][j 8]
    const int idx = (b - 576) * 256 + threadIdx.x;
    const int j = idx & 7;
    const int n = (idx >> 3) & 15;
    const int kg = (idx >> 7) & 3;
    const int pos = idx >> 9;
    const int ci = kg * 8 + j;
    float v = 0.f;
    if (n < 8) v = w3[(n * 32 + ci) * 9 + pos];
    pb3[idx] = f2bf(v);
  }
}

// ---------------------------------------------------------------------------
// conv1: implicit GEMM bf16 MFMA, double-buffered A staging.
// In: cost_t [128][256][224]. Out: o1_t NHWC bf16 [128][256][64].
// ---------------------------------------------------------------------------
__global__ __launch_bounds__(256) void conv1_mfma_kernel(
    const unsigned short* __restrict__ cost_t,
    const unsigned short* __restrict__ pw,  // [7][9][4][64][8]
    const float* __restrict__ bias, const float* __restrict__ gam,
    const float* __restrict__ bet, const float* __restrict__ mean,
    const float* __restrict__ var, unsigned short* __restrict__ out_t) {
  __shared__ unsigned short a_sh[2][3 * 66 * 40];  // 31680 B
  const int tid = threadIdx.x;
  const int lane = tid & 63;
  const int w = tid >> 6;
  const int y = blockIdx.y;
  const int x0 = blockIdx.x * 64;
  const int m0 = (w >> 1) * 32;
  const int n0 = (w & 1) * 32;
  const int col = lane & 15;
  const int kg = lane >> 4;

  // precompute per-thread staging slots (chunk-independent)
  long goff[4];
  int laddr[4];
  bool gvalid[4], lvalid[4];
#pragma unroll
  for (int it = 0; it < 4; ++it) {
    const int i = tid + it * 256;
    lvalid[it] = i < 792;  // 3*66*4
    const int row = i / 264;
    const int rem = i % 264;
    const int xx = rem >> 2;
    const int q = rem & 3;
    const int gy = y + row - 1;
    const int gx = x0 - 1 + xx;
    gvalid[it] = lvalid[it] && gy >= 0 && gy < HH && gx >= 0 && gx < WW;
    goff[it] = gvalid[it] ? (long)(gy * WW + gx) * 224 + q * 8 : 0;
    laddr[it] = (row * 66 + xx) * 40 + q * 8;
  }

  f32x4 acc[2][2];
#pragma unroll
  for (int i = 0; i < 2; ++i)
#pragma unroll
    for (int jj = 0; jj < 2; ++jj) acc[i][jj] = 0.f;

  const bf16x8* pwv = (const bf16x8*)pw;
  const bf16x8 zero = {0, 0, 0, 0, 0, 0, 0, 0};
  bf16x8 stg[4];

  // prologue: stage chunk 0
#pragma unroll
  for (int it = 0; it < 4; ++it)
    stg[it] = gvalid[it] ? *reinterpret_cast<const bf16x8*>(&cost_t[goff[it]])
                         : zero;
#pragma unroll
  for (int it = 0; it < 4; ++it)
    if (lvalid[it])
      *reinterpret_cast<bf16x8*>(&a_sh[0][laddr[it]]) = stg[it];
  __syncthreads();

  for (int chunk = 0; chunk < 7; ++chunk) {
    const int buf = chunk & 1;
    if (chunk < 6) {  // issue next chunk's loads (latency hidden by MFMAs)
#pragma unroll
      for (int it = 0; it < 4; ++it)
        stg[it] = gvalid[it] ? *reinterpret_cast<const bf16x8*>(
                                   &cost_t[goff[it] + (chunk + 1) * 32])
                             : zero;
    }
    const bf16x8* av = (const bf16x8*)a_sh[buf];
#pragma unroll
    for (int pos = 0; pos < 9; ++pos) {
      const int ky = pos / 3;
      const int kx = pos % 3;
      const int bbase = ((chunk * 9 + pos) * 4 + kg) * 64;
      const bf16x8 b0v = pwv[bbase + n0 + col];
      const bf16x8 b1v = pwv[bbase + n0 + 16 + col];
      const bf16x8 a0v = av[(ky * 66 + m0 + col + kx) * 5 + kg];
      const bf16x8 a1v = av[(ky * 66 + m0 + 16 + col + kx) * 5 + kg];
      acc[0][0] = __builtin_amdgcn_mfma_f32_16x16x32_bf16(a0v, b0v, acc[0][0], 0, 0, 0);
      acc[0][1] = __builtin_amdgcn_mfma_f32_16x16x32_bf16(a0v, b1v, acc[0][1], 0, 0, 0);
      acc[1][0] = __builtin_amdgcn_mfma_f32_16x16x32_bf16(a1v, b0v, acc[1][0], 0, 0, 0);
      acc[1][1] = __builtin_amdgcn_mfma_f32_16x16x32_bf16(a1v, b1v, acc[1][1], 0, 0, 0);
    }
    if (chunk < 6) {
#pragma unroll
      for (int it = 0; it < 4; ++it)
        if (lvalid[it])
          *reinterpret_cast<bf16x8*>(&a_sh[buf ^ 1][laddr[it]]) = stg[it];
      __syncthreads();
    }
  }

  const int rbase = kg * 4;
#pragma unroll
  for (int nf = 0; nf < 2; ++nf) {
    const int c = n0 + nf * 16 + col;
    const float inv = rsqrtf(var[c] + 1e-5f);
    const float sc = gam[c] * inv;
    const float sh = bet[c] - mean[c] * sc;
    const float bb = bias[c];
#pragma unroll
    for (int mf = 0; mf < 2; ++mf) {
#pragma unroll
      for (int r = 0; r < 4; ++r) {
        const int m = m0 + mf * 16 + rbase + r;
        float vv = (acc[mf][nf][r] + bb) * sc + sh;
        vv = fmaxf(vv, 0.f);
        out_t[((y * WW + x0 + m) << 6) + c] = f2bf(vv);
      }
    }
  }
}

// ---------------------------------------------------------------------------
// conv2: 64->32, NHWC bf16 in/out. XOR-swizzled A-tile.
// ---------------------------------------------------------------------------
__global__ __launch_bounds__(256) void conv2_mfma_kernel(
    const unsigned short* __restrict__ in_t,  // [128][256][64]
    const unsigned short* __restrict__ pb,    // [9][2][4][32][8]
    const float* __restrict__ bias, const float* __restrict__ gam,
    const float* __restrict__ bet, const float* __restrict__ mean,
    const float* __restrict__ var, unsigned short* __restrict__ out_t) {
  __shared__ unsigned short a_sh[3 * 66 * 64];  // 25344 B
  char* const ab = (char*)a_sh;
  const int tid = threadIdx.x;
  const int lane = tid & 63;
  const int w = tid >> 6;
  const int y = blockIdx.y;
  const int x0 = blockIdx.x * 64;
  const int m0 = (w >> 1) * 32;
  const int n0 = (w & 1) * 16;
  const int col = lane & 15;
  const int kg = lane >> 4;

  f32x4 acc[2];
  acc[0] = 0.f;
  acc[1] = 0.f;

  for (int i = tid; i < 1584; i += 256) {  // 3*66*8
    const int r = i >> 3;
    const int q = i & 7;
    const int rowy = r / 66;
    const int xx = r % 66;
    const int gy = y + rowy - 1;
    const int gx = x0 - 1 + xx;
    bf16x8 v = {0, 0, 0, 0, 0, 0, 0, 0};
    if (gy >= 0 && gy < HH && gx >= 0 && gx < WW)
      v = *reinterpret_cast<const bf16x8*>(&in_t[((gy * WW + gx) << 6) + q * 8]);
    const int byte = ((r << 7) + (q << 4)) ^ ((r & 7) << 4);
    *reinterpret_cast<bf16x8*>(ab + byte) = v;
  }
  __syncthreads();

  const bf16x8* pbv = (const bf16x8*)pb;
#pragma unroll
  for (int pos = 0; pos < 9; ++pos) {
    const int ky = pos / 3;
    const int kx = pos % 3;
#pragma unroll
    for (int kc = 0; kc < 2; ++kc) {
      const bf16x8 bv = pbv[((pos * 2 + kc) * 4 + kg) * 32 + n0 + col];
#pragma unroll
      for (int mf = 0; mf < 2; ++mf) {
        const int r = ky * 66 + m0 + mf * 16 + col + kx;
        const int byte = ((r << 7) + (kc << 6) + (kg << 4)) ^ ((r & 7) << 4);
        const bf16x8 av = *reinterpret_cast<const bf16x8*>(ab + byte);
        acc[mf] = __builtin_amdgcn_mfma_f32_16x16x32_bf16(av, bv, acc[mf], 0, 0, 0);
      }
    }
  }

  const int c = n0 + col;
  const float inv = rsqrtf(var[c] + 1e-5f);
  const float sc = gam[c] * inv;
  const float sh = bet[c] - mean[c] * sc;
  const float bb = bias[c];
  const int rbase = kg * 4;
#pragma unroll
  for (int mf = 0; mf < 2; ++mf) {
#pragma unroll
    for (int r = 0; r < 4; ++r) {
      const int m = m0 + mf * 16 + rbase + r;
      float vv = (acc[mf][r] + bb) * sc + sh;
      vv = fmaxf(vv, 0.f);
      out_t[((y * WW + x0 + m) << 5) + c] = f2bf(vv);
    }
  }
}

// ---------------------------------------------------------------------------
// conv3: 32->8 (N padded to 16), NHWC bf16.
// ---------------------------------------------------------------------------
__global__ __launch_bounds__(256) void conv3_mfma_kernel(
    const unsigned short* __restrict__ in_t,  // [128][256][32]
    const unsigned short* __restrict__ pb,    // [9][4][16][8]
    const float* __restrict__ bias, const float* __restrict__ gam,
    const float* __restrict__ bet, const float* __restrict__ mean,
    const float* __restrict__ var, unsigned short* __restrict__ out_t) {
  __shared__ unsigned short a_sh[3 * 66 * 32];  // 12672 B
  char* const ab = (char*)a_sh;
  const int tid = threadIdx.x;
  const int lane = tid & 63;
  const int w = tid >> 6;
  const int y = blockIdx.y;
  const int x0 = blockIdx.x * 64;
  const int m0 = w * 16;
  const int col = lane & 15;
  const int kg = lane >> 4;

  f32x4 acc = 0.f;

  for (int i = tid; i < 792; i += 256) {  // 3*66*4
    const int r = i >> 2;
    const int q = i & 3;
    const int rowy = r / 66;
    const int xx = r % 66;
    const int gy = y + rowy - 1;
    const int gx = x0 - 1 + xx;
    bf16x8 v = {0, 0, 0, 0, 0, 0, 0, 0};
    if (gy >= 0 && gy < HH && gx >= 0 && gx < WW)
      v = *reinterpret_cast<const bf16x8*>(&in_t[((gy * WW + gx) << 5) + q * 8]);
    const int byte = ((r << 6) + (q << 4)) ^ ((r & 3) << 4);
    *reinterpret_cast<bf16x8*>(ab + byte) = v;
  }
  __syncthreads();

  const bf16x8* pbv = (const bf16x8*)pb;
#pragma unroll
  for (int pos = 0; pos < 9; ++pos) {
    const int ky = pos / 3;
    const int kx = pos % 3;
    const bf16x8 bv = pbv[(pos * 4 + kg) * 16 + col];
    const int r = ky * 66 + m0 + col + kx;
    const int byte = ((r << 6) + (kg << 4)) ^ ((r & 3) << 4);
    const bf16x8 av = *reinterpret_cast<const bf16x8*>(ab + byte);
    acc = __builtin_amdgcn_mfma_f32_16x16x32_bf16(av, bv, acc, 0, 0, 0);
  }

  if (col < 8) {
    const int c = col;
    const float inv = rsqrtf(var[c] + 1e-5f);
    const float sc = gam[c] * inv;
    const float sh = bet[c] - mean[c] * sc;
    const float bb = bias[c];
    const int rbase = kg * 4;
#pragma unroll
    for (int r = 0; r < 4; ++r) {
      const int m = m0 + rbase + r;
      float vv = (acc[r] + bb) * sc + sh;
      vv = fmaxf(vv, 0.f);
      out_t[((y * WW + x0 + m) << 3) + c] = f2bf(vv);
    }
  }
}

// ---------------------------------------------------------------------------
// conv4: 8->1, per-pixel direct (o3_t is L2-resident, 512 KB).
// ---------------------------------------------------------------------------
__global__ __launch_bounds__(256) void conv4_kernel(
    const unsigned short* __restrict__ in_t, const float* __restrict__ w4,
    const float* __restrict__ b4, float* __restrict__ out) {
  const int p = blockIdx.x * 256 + threadIdx.x;
  const int y = p >> 8;
  const int x = p & 255;

  float wr[3][3][8];
#pragma unroll
  for (int ci = 0; ci < 8; ++ci)
#pragma unroll
    for (int ky = 0; ky < 3; ++ky)
#pragma unroll
      for (int kx = 0; kx < 3; ++kx) wr[ky][kx][ci] = w4[(ci * 3 + ky) * 3 + kx];

  float acc = b4[0];
#pragma unroll
  for (int ky = 0; ky < 3; ++ky) {
    const int gy = y + ky - 1;
    if (gy < 0 || gy >= HH) continue;
#pragma unroll
    for (int kx = 0; kx < 3; ++kx) {
      const int gx = x + kx - 1;
      if (gx < 0 || gx >= WW) continue;
      const bf16x8 v =
          *reinterpret_cast<const bf16x8*>(&in_t[((gy << 8) + gx) << 3]);
#pragma unroll
      for (int ci = 0; ci < 8; ++ci) acc += bf2f(v[ci]) * wr[ky][kx][ci];
    }
  }
  out[p] = acc;
}

// ---------------------------------------------------------------------------
extern "C" void kernel_launch(void* const* d_in, const int* in_sizes, int n_in,
                              void* d_out, int out_size, void* d_ws,
                              size_t ws_size, hipStream_t stream) {
  const float* left = (const float*)d_in[0];
  const float* right = (const float*)d_in[1];
  const float* w1 = (const float*)d_in[2];
  const float* b1 = (const float*)d_in[3];
  const float* g1 = (const float*)d_in[4];
  const float* be1 = (const float*)d_in[5];
  const float* m1 = (const float*)d_in[6];
  const float* v1 = (const float*)d_in[7];
  const float* w2 = (const float*)d_in[8];
  const float* b2 = (const float*)d_in[9];
  const float* g2 = (const float*)d_in[10];
  const float* be2 = (const float*)d_in[11];
  const float* m2 = (const float*)d_in[12];
  const float* v2 = (const float*)d_in[13];
  const float* w3 = (const float*)d_in[14];
  const float* b3 = (const float*)d_in[15];
  const float* g3 = (const float*)d_in[16];
  const float* be3 = (const float*)d_in[17];
  const float* m3 = (const float*)d_in[18];
  const float* v3 = (const float*)d_in[19];
  const float* w4 = (const float*)d_in[20];
  const float* b4 = (const float*)d_in[21];

  // Workspace:
  //  [0, 14680064)   cost_t bf16 [128][256][224]
  //  region:
  //    +0        pw1 (258048, reserve 262144)
  //    +262144   pb2 (36864, reserve 65536)
  //    +327680   pb3 (9216, reserve 65536)
  //    +393216   o1_t bf16 [128][256][64] (4194304)
  //    +4587520  o2_t bf16 [128][256][32] (2097152)
  //    +6684672  o3_t bf16 [128][256][8]  (524288)
  char* ws = (char*)d_ws;
  unsigned short* cost_t = (unsigned short*)ws;
  char* region = ws + 14680064;
  unsigned short* pw1 = (unsigned short*)(region + 0);
  unsigned short* pb2 = (unsigned short*)(region + 262144);
  unsigned short* pb3 = (unsigned short*)(region + 327680);
  unsigned short* o1t = (unsigned short*)(region + 393216);
  unsigned short* o2t = (unsigned short*)(region + 4587520);
  unsigned short* o3t = (unsigned short*)(region + 6684672);
  float* o4 = (float*)d_out;

  pack_all_kernel<<<594, 256, 0, stream>>>(w1, w2, w3, pw1, pb2, pb3);
  cost_volume_mfma_kernel<<<dim3(4, HH), 256, 0, stream>>>(left, right, cost_t);
  conv1_mfma_kernel<<<dim3(4, HH), 256, 0, stream>>>(cost_t, pw1, b1, g1, be1,
                                                     m1, v1, o1t);
  conv2_mfma_kernel<<<dim3(4, HH), 256, 0, stream>>>(o1t, pb2, b2, g2, be2, m2,
                                                     v2, o2t);
  conv3_mfma_kernel<<<dim3(4, HH), 256, 0, stream>>>(o2t, pb3, b3, g3, be3, m3,
                                                     v3, o3t);
  conv4_kernel<<<128, 256, 0, stream>>>(o3t, w4, b4, o4);
}